// Round 1
// baseline (2424.409 us; speedup 1.0000x reference)
//
#include <hip/hip_runtime.h>

// LSTMNet: B=1024, T=2048, H=64, NC=10, input_size=1.
// 1 wave per batch row (1024 waves = 1 wave/SIMD over the whole chip).
// Lane j owns hidden unit j: h[j], c[j], and the 4 gate rows of W_hh it needs
// (256 floats) live in VGPRs. Per step, h is exchanged through a per-wave LDS
// row (broadcast reads, conflict-free). fp32 throughout (matches reference).

#define T_STEPS 2048
#define HID 64
#define NCLS 10

__device__ __forceinline__ float sigm(float x) {
    // 1 / (1 + exp(-x)) via exp2
    float e = __builtin_amdgcn_exp2f(-1.4426950408889634f * x);
    return __builtin_amdgcn_rcpf(1.0f + e);
}

__device__ __forceinline__ float tanh_f(float x) {
    // tanh(x) = 2*sigmoid(2x) - 1 = 2/(1+exp(-2x)) - 1
    float e = __builtin_amdgcn_exp2f(-2.8853900817779268f * x);
    return fmaf(2.0f, __builtin_amdgcn_rcpf(1.0f + e), -1.0f);
}

__global__ __launch_bounds__(256, 1) void lstm_net_kernel(
    const float* __restrict__ x,      // [B, 1, T]
    const float* __restrict__ W_ih,   // [256, 1]
    const float* __restrict__ W_hh,   // [256, 64]
    const float* __restrict__ b_ih,   // [256]
    const float* __restrict__ b_hh,   // [256]
    const float* __restrict__ fc1_w,  // [64, 64]
    const float* __restrict__ fc1_b,  // [64]
    const float* __restrict__ fc2_w,  // [10, 64]
    const float* __restrict__ fc2_b,  // [10]
    float* __restrict__ out)          // [B, 10]
{
    const int lane = threadIdx.x & 63;
    const int wv   = threadIdx.x >> 6;
    const int b    = blockIdx.x * 4 + wv;

    __shared__ __align__(16) float hbuf[4][HID];

    // --- preload recurrent weights into VGPRs: wreg[q][j] = W_hh[q*64+lane][j]
    float wreg[4][HID];
    #pragma unroll
    for (int q = 0; q < 4; ++q) {
        const float4* wrow = reinterpret_cast<const float4*>(W_hh + (q * HID + lane) * HID);
        #pragma unroll
        for (int jj = 0; jj < HID / 4; ++jj) {
            float4 v = wrow[jj];
            wreg[q][4 * jj + 0] = v.x;
            wreg[q][4 * jj + 1] = v.y;
            wreg[q][4 * jj + 2] = v.z;
            wreg[q][4 * jj + 3] = v.w;
        }
    }
    float wih[4], bsum[4];
    #pragma unroll
    for (int q = 0; q < 4; ++q) {
        wih[q]  = W_ih[q * HID + lane];
        bsum[q] = b_ih[q * HID + lane] + b_hh[q * HID + lane];
    }

    const float* xrow = x + (size_t)b * T_STEPS;
    const float4* hb4 = reinterpret_cast<const float4*>(&hbuf[wv][0]);

    float h = 0.0f, c = 0.0f;
    float xt = xrow[0];

    #pragma unroll 1
    for (int t = 0; t < T_STEPS; ++t) {
        // prefetch next step's scalar input (wave-uniform)
        float xn = xrow[(t + 1 < T_STEPS) ? (t + 1) : t];

        // publish h to this wave's LDS row (intra-wave only; lockstep, no barrier)
        hbuf[wv][lane] = h;

        float a0 = fmaf(xt, wih[0], bsum[0]);
        float a1 = fmaf(xt, wih[1], bsum[1]);
        float a2 = fmaf(xt, wih[2], bsum[2]);
        float a3 = fmaf(xt, wih[3], bsum[3]);

        #pragma unroll
        for (int jj = 0; jj < HID / 4; ++jj) {
            float4 hv = hb4[jj];  // broadcast read, conflict-free
            float he[4] = {hv.x, hv.y, hv.z, hv.w};
            #pragma unroll
            for (int e = 0; e < 4; ++e) {
                a0 = fmaf(he[e], wreg[0][4 * jj + e], a0);
                a1 = fmaf(he[e], wreg[1][4 * jj + e], a1);
                a2 = fmaf(he[e], wreg[2][4 * jj + e], a2);
                a3 = fmaf(he[e], wreg[3][4 * jj + e], a3);
            }
        }

        float ig = sigm(a0);
        float fg = sigm(a1);
        float gg = tanh_f(a2);
        float og = sigm(a3);
        c = fmaf(fg, c, ig * gg);
        h = og * tanh_f(c);
        xt = xn;
    }

    // --- epilogue: fc1 (relu) then fc2, per wave ---
    hbuf[wv][lane] = h;  // final hidden state

    float acc = fc1_b[lane];
    const float4* w1 = reinterpret_cast<const float4*>(fc1_w + lane * HID);
    #pragma unroll
    for (int kk = 0; kk < HID / 4; ++kk) {
        float4 wvv = w1[kk];
        float4 hv  = hb4[kk];
        acc = fmaf(hv.x, wvv.x, acc);
        acc = fmaf(hv.y, wvv.y, acc);
        acc = fmaf(hv.z, wvv.z, acc);
        acc = fmaf(hv.w, wvv.w, acc);
    }
    float hr = fmaxf(acc, 0.0f);

    // reuse hbuf: all lanes finished reading h above (wave lockstep)
    hbuf[wv][lane] = hr;

    if (lane < NCLS) {
        float a2 = fc2_b[lane];
        const float* w2 = fc2_w + lane * HID;
        #pragma unroll
        for (int j = 0; j < HID; ++j) {
            a2 = fmaf(hbuf[wv][j], w2[j], a2);
        }
        out[(size_t)b * NCLS + lane] = a2;
    }
}

extern "C" void kernel_launch(void* const* d_in, const int* in_sizes, int n_in,
                              void* d_out, int out_size, void* d_ws, size_t ws_size,
                              hipStream_t stream) {
    const float* x     = (const float*)d_in[0];
    const float* W_ih  = (const float*)d_in[1];
    const float* W_hh  = (const float*)d_in[2];
    const float* b_ih  = (const float*)d_in[3];
    const float* b_hh  = (const float*)d_in[4];
    const float* fc1_w = (const float*)d_in[5];
    const float* fc1_b = (const float*)d_in[6];
    const float* fc2_w = (const float*)d_in[7];
    const float* fc2_b = (const float*)d_in[8];
    float* out = (float*)d_out;

    dim3 grid(256);   // 1024 batch rows / 4 waves per block
    dim3 block(256);  // 4 waves
    lstm_net_kernel<<<grid, block, 0, stream>>>(x, W_ih, W_hh, b_ih, b_hh,
                                                fc1_w, fc1_b, fc2_w, fc2_b, out);
}

// Round 2
// 1888.448 us; speedup vs baseline: 1.2838x; 1.2838x over previous
//
#include <hip/hip_runtime.h>

// LSTMNet: B=1024, T=2048, H=64, NC=10, input_size=1.
// 1 wave (64 threads) per batch row, grid=1024 = 1 wave per SIMD chip-wide.
// Lane j owns hidden unit j: h[j], c[j], and its 4 gate rows of W_hh
// (256 floats = 128 float2 pairs) in VGPRs. Weights held as float2 so the
// dot products lower to v_pk_fma_f32 (2 fp32 FMAs/instr, gfx90a+).
// h exchange via per-block LDS row with wave-uniform (broadcast) reads.
// __launch_bounds__(64,1) + amdgpu_waves_per_eu(1,1): 512-VGPR budget so the
// ~290-VGPR working set stays register-resident (R1 failure: spilled at 144).

#define T_STEPS 2048
#define HID 64
#define NCLS 10

typedef float v2f __attribute__((ext_vector_type(2)));

__device__ __forceinline__ float sigm(float x) {
    float e = __builtin_amdgcn_exp2f(-1.4426950408889634f * x);
    return __builtin_amdgcn_rcpf(1.0f + e);
}

__device__ __forceinline__ float tanh_f(float x) {
    float e = __builtin_amdgcn_exp2f(-2.8853900817779268f * x);
    return fmaf(2.0f, __builtin_amdgcn_rcpf(1.0f + e), -1.0f);
}

__global__ __launch_bounds__(64, 1) __attribute__((amdgpu_waves_per_eu(1, 1)))
void lstm_net_kernel(
    const float* __restrict__ x,      // [B, 1, T]
    const float* __restrict__ W_ih,   // [256, 1]
    const float* __restrict__ W_hh,   // [256, 64]
    const float* __restrict__ b_ih,   // [256]
    const float* __restrict__ b_hh,   // [256]
    const float* __restrict__ fc1_w,  // [64, 64]
    const float* __restrict__ fc1_b,  // [64]
    const float* __restrict__ fc2_w,  // [10, 64]
    const float* __restrict__ fc2_b,  // [10]
    float* __restrict__ out)          // [B, 10]
{
    const int lane = threadIdx.x & 63;
    const int b    = blockIdx.x;

    __shared__ __align__(16) float hbuf[HID];

    // Recurrent weights for this lane's 4 gate rows, as float2 pairs.
    // wreg2[q][p] = (W_hh[q*64+lane][2p], W_hh[q*64+lane][2p+1])
    v2f wreg2[4][HID / 2];
    #pragma unroll
    for (int q = 0; q < 4; ++q) {
        const float4* wrow = reinterpret_cast<const float4*>(W_hh + (q * HID + lane) * HID);
        #pragma unroll
        for (int jj = 0; jj < HID / 4; ++jj) {
            float4 v = wrow[jj];
            wreg2[q][2 * jj + 0] = (v2f){v.x, v.y};
            wreg2[q][2 * jj + 1] = (v2f){v.z, v.w};
        }
    }
    float wih[4], bsum[4];
    #pragma unroll
    for (int q = 0; q < 4; ++q) {
        wih[q]  = W_ih[q * HID + lane];
        bsum[q] = b_ih[q * HID + lane] + b_hh[q * HID + lane];
    }

    const float* xrow = x + (size_t)b * T_STEPS;
    const float4* hb4 = reinterpret_cast<const float4*>(&hbuf[0]);

    float h = 0.0f, c = 0.0f;
    float xt = xrow[0];

    #pragma unroll 1
    for (int t = 0; t < T_STEPS; ++t) {
        float xn = xrow[(t + 1 < T_STEPS) ? (t + 1) : t];  // wave-uniform prefetch

        hbuf[lane] = h;  // publish h (single wave: lockstep, no barrier)

        // 2 independent v2f accumulator chains per gate (8 chains, 16 deep)
        v2f acc[4][2];
        #pragma unroll
        for (int q = 0; q < 4; ++q) {
            acc[q][0] = (v2f){fmaf(xt, wih[q], bsum[q]), 0.0f};
            acc[q][1] = (v2f){0.0f, 0.0f};
        }

        #pragma unroll
        for (int jj = 0; jj < HID / 4; ++jj) {
            float4 hv = hb4[jj];  // wave-uniform address: LDS broadcast read
            v2f h01 = (v2f){hv.x, hv.y};
            v2f h23 = (v2f){hv.z, hv.w};
            #pragma unroll
            for (int q = 0; q < 4; ++q) {
                acc[q][0] = __builtin_elementwise_fma(wreg2[q][2 * jj + 0], h01, acc[q][0]);
                acc[q][1] = __builtin_elementwise_fma(wreg2[q][2 * jj + 1], h23, acc[q][1]);
            }
        }

        float a0 = acc[0][0].x + acc[0][0].y + acc[0][1].x + acc[0][1].y;
        float a1 = acc[1][0].x + acc[1][0].y + acc[1][1].x + acc[1][1].y;
        float a2 = acc[2][0].x + acc[2][0].y + acc[2][1].x + acc[2][1].y;
        float a3 = acc[3][0].x + acc[3][0].y + acc[3][1].x + acc[3][1].y;

        float ig = sigm(a0);
        float fg = sigm(a1);
        float gg = tanh_f(a2);
        float og = sigm(a3);
        c = fmaf(fg, c, ig * gg);
        h = og * tanh_f(c);
        xt = xn;
    }

    // --- epilogue: fc1 (relu) then fc2 ---
    hbuf[lane] = h;

    float acc1 = fc1_b[lane];
    const float4* w1 = reinterpret_cast<const float4*>(fc1_w + lane * HID);
    #pragma unroll
    for (int kk = 0; kk < HID / 4; ++kk) {
        float4 wvv = w1[kk];
        float4 hv  = hb4[kk];
        acc1 = fmaf(hv.x, wvv.x, acc1);
        acc1 = fmaf(hv.y, wvv.y, acc1);
        acc1 = fmaf(hv.z, wvv.z, acc1);
        acc1 = fmaf(hv.w, wvv.w, acc1);
    }
    float hr = fmaxf(acc1, 0.0f);

    hbuf[lane] = hr;  // wave lockstep: all reads of h above are done

    if (lane < NCLS) {
        float a = fc2_b[lane];
        const float* w2 = fc2_w + lane * HID;
        #pragma unroll
        for (int j = 0; j < HID; ++j) {
            a = fmaf(hbuf[j], w2[j], a);
        }
        out[(size_t)b * NCLS + lane] = a;
    }
}

extern "C" void kernel_launch(void* const* d_in, const int* in_sizes, int n_in,
                              void* d_out, int out_size, void* d_ws, size_t ws_size,
                              hipStream_t stream) {
    const float* x     = (const float*)d_in[0];
    const float* W_ih  = (const float*)d_in[1];
    const float* W_hh  = (const float*)d_in[2];
    const float* b_ih  = (const float*)d_in[3];
    const float* b_hh  = (const float*)d_in[4];
    const float* fc1_w = (const float*)d_in[5];
    const float* fc1_b = (const float*)d_in[6];
    const float* fc2_w = (const float*)d_in[7];
    const float* fc2_b = (const float*)d_in[8];
    float* out = (float*)d_out;

    dim3 grid(1024);  // 1 block = 1 wave = 1 batch row
    dim3 block(64);
    lstm_net_kernel<<<grid, block, 0, stream>>>(x, W_ih, W_hh, b_ih, b_hh,
                                                fc1_w, fc1_b, fc2_w, fc2_b, out);
}

// Round 3
// 1826.654 us; speedup vs baseline: 1.3272x; 1.0338x over previous
//
#include <hip/hip_runtime.h>

// LSTMNet: B=1024, T=2048, H=64, NC=10, input_size=1.
// 1 wave (64 threads) per batch row, grid=1024 = 1 wave per SIMD chip-wide.
// Lane k owns hidden unit k: h[k], c[k], and its 4 gate rows of W_hh
// (256 floats = 128 v2f pairs) in VGPRs, lowered to v_pk_fma_f32.
// R1/R2 failure: compiler rematerialized the invariant W_hh loads inside the
// t-loop (VGPR_Count stuck at ~148, step cost VMEM-bound). Fix: opaque
// inline-asm pin on every weight register pair — no longer a load result,
// allocator must keep them live. Budget 512 VGPR at 1 wave/SIMD.

#define T_STEPS 2048
#define HID 64
#define NCLS 10

typedef float v2f __attribute__((ext_vector_type(2)));

__device__ __forceinline__ float sigm(float x) {
    float e = __builtin_amdgcn_exp2f(-1.4426950408889634f * x);
    return __builtin_amdgcn_rcpf(1.0f + e);
}

__device__ __forceinline__ float tanh_f(float x) {
    float e = __builtin_amdgcn_exp2f(-2.8853900817779268f * x);
    return fmaf(2.0f, __builtin_amdgcn_rcpf(1.0f + e), -1.0f);
}

__global__ __launch_bounds__(64, 1) __attribute__((amdgpu_waves_per_eu(1, 1)))
void lstm_net_kernel(
    const float* __restrict__ x,      // [B, 1, T]
    const float* __restrict__ W_ih,   // [256, 1]
    const float* __restrict__ W_hh,   // [256, 64]
    const float* __restrict__ b_ih,   // [256]
    const float* __restrict__ b_hh,   // [256]
    const float* __restrict__ fc1_w,  // [64, 64]
    const float* __restrict__ fc1_b,  // [64]
    const float* __restrict__ fc2_w,  // [10, 64]
    const float* __restrict__ fc2_b,  // [10]
    float* __restrict__ out)          // [B, 10]
{
    const int lane = threadIdx.x & 63;
    const int b    = blockIdx.x;

    __shared__ __align__(16) float hbuf[HID];

    // Recurrent weights for this lane's 4 gate rows, as v2f pairs.
    v2f wreg2[4][HID / 2];
    #pragma unroll
    for (int q = 0; q < 4; ++q) {
        const float4* wrow = reinterpret_cast<const float4*>(W_hh + (q * HID + lane) * HID);
        #pragma unroll
        for (int jj = 0; jj < HID / 4; ++jj) {
            float4 v = wrow[jj];
            wreg2[q][2 * jj + 0] = (v2f){v.x, v.y};
            wreg2[q][2 * jj + 1] = (v2f){v.z, v.w};
        }
    }
    // Opaque pin: values are no longer rematerializable loads; the allocator
    // must keep all 128 register pairs live across the t-loop.
    #pragma unroll
    for (int q = 0; q < 4; ++q) {
        #pragma unroll
        for (int p = 0; p < HID / 2; ++p) {
            asm volatile("" : "+v"(wreg2[q][p]));
        }
    }

    float wih[4], bsum[4];
    #pragma unroll
    for (int q = 0; q < 4; ++q) {
        wih[q]  = W_ih[q * HID + lane];
        bsum[q] = b_ih[q * HID + lane] + b_hh[q * HID + lane];
    }

    const float* xrow = x + (size_t)b * T_STEPS;
    const float4* hb4 = reinterpret_cast<const float4*>(&hbuf[0]);

    float h = 0.0f, c = 0.0f;
    float xt = xrow[0];

    #pragma unroll 1
    for (int t = 0; t < T_STEPS; ++t) {
        float xn = xrow[(t + 1 < T_STEPS) ? (t + 1) : t];  // wave-uniform prefetch

        hbuf[lane] = h;  // publish h (single wave: lockstep; compiler inserts lgkm wait)

        // 2 independent v2f accumulator chains per gate (8 chains, 16 deep)
        v2f acc[4][2];
        #pragma unroll
        for (int q = 0; q < 4; ++q) {
            acc[q][0] = (v2f){fmaf(xt, wih[q], bsum[q]), 0.0f};
            acc[q][1] = (v2f){0.0f, 0.0f};
        }

        #pragma unroll
        for (int jj = 0; jj < HID / 4; ++jj) {
            float4 hv = hb4[jj];  // wave-uniform address: LDS broadcast read
            v2f h01 = (v2f){hv.x, hv.y};
            v2f h23 = (v2f){hv.z, hv.w};
            #pragma unroll
            for (int q = 0; q < 4; ++q) {
                acc[q][0] = __builtin_elementwise_fma(wreg2[q][2 * jj + 0], h01, acc[q][0]);
                acc[q][1] = __builtin_elementwise_fma(wreg2[q][2 * jj + 1], h23, acc[q][1]);
            }
        }

        float a0 = acc[0][0].x + acc[0][0].y + acc[0][1].x + acc[0][1].y;
        float a1 = acc[1][0].x + acc[1][0].y + acc[1][1].x + acc[1][1].y;
        float a2 = acc[2][0].x + acc[2][0].y + acc[2][1].x + acc[2][1].y;
        float a3 = acc[3][0].x + acc[3][0].y + acc[3][1].x + acc[3][1].y;

        float ig = sigm(a0);
        float fg = sigm(a1);
        float gg = tanh_f(a2);
        float og = sigm(a3);
        c = fmaf(fg, c, ig * gg);
        h = og * tanh_f(c);
        xt = xn;
    }

    // --- epilogue: fc1 (relu) then fc2 ---
    hbuf[lane] = h;

    float acc1 = fc1_b[lane];
    const float4* w1 = reinterpret_cast<const float4*>(fc1_w + lane * HID);
    #pragma unroll
    for (int kk = 0; kk < HID / 4; ++kk) {
        float4 wvv = w1[kk];
        float4 hv  = hb4[kk];
        acc1 = fmaf(hv.x, wvv.x, acc1);
        acc1 = fmaf(hv.y, wvv.y, acc1);
        acc1 = fmaf(hv.z, wvv.z, acc1);
        acc1 = fmaf(hv.w, wvv.w, acc1);
    }
    float hr = fmaxf(acc1, 0.0f);

    hbuf[lane] = hr;  // wave lockstep: all reads of h above are done

    if (lane < NCLS) {
        float a = fc2_b[lane];
        const float* w2 = fc2_w + lane * HID;
        #pragma unroll
        for (int j = 0; j < HID; ++j) {
            a = fmaf(hbuf[j], w2[j], a);
        }
        out[(size_t)b * NCLS + lane] = a;
    }
}

extern "C" void kernel_launch(void* const* d_in, const int* in_sizes, int n_in,
                              void* d_out, int out_size, void* d_ws, size_t ws_size,
                              hipStream_t stream) {
    const float* x     = (const float*)d_in[0];
    const float* W_ih  = (const float*)d_in[1];
    const float* W_hh  = (const float*)d_in[2];
    const float* b_ih  = (const float*)d_in[3];
    const float* b_hh  = (const float*)d_in[4];
    const float* fc1_w = (const float*)d_in[5];
    const float* fc1_b = (const float*)d_in[6];
    const float* fc2_w = (const float*)d_in[7];
    const float* fc2_b = (const float*)d_in[8];
    float* out = (float*)d_out;

    dim3 grid(1024);  // 1 block = 1 wave = 1 batch row
    dim3 block(64);
    lstm_net_kernel<<<grid, block, 0, stream>>>(x, W_ih, W_hh, b_ih, b_hh,
                                                fc1_w, fc1_b, fc2_w, fc2_b, out);
}

// Round 4
// 1431.846 us; speedup vs baseline: 1.6932x; 1.2757x over previous
//
#include <hip/hip_runtime.h>

// LSTMNet: B=1024, T=2048, H=64, NC=10, input_size=1.
// R1-R3 lesson: the allocator refuses >~148 VGPRs and spills — a 256-weight/lane
// design can't be made register-resident. Restructure: gate-split.
//   block = 256 threads = 4 waves = ONE batch row; grid = 1024.
//   Wave q, lane k owns W_hh row (q*64+k): 64 weights = 32 v2f (~100 VGPR total).
//   Per step: all waves read h (16 broadcast ds_read_b128), 32 v_pk_fma_f32,
//   write gate to LDS; barrier; update wave (blockIdx&3, rotates across SIMDs
//   for balance) does activations, carries c, writes h; barrier.
// __launch_bounds__(256,4): 4 blocks/CU = 4 waves/SIMD, VGPR cap 128.

#define T_STEPS 2048
#define HID 64
#define NCLS 10

typedef float v2f __attribute__((ext_vector_type(2)));

__device__ __forceinline__ float sigm(float x) {
    float e = __builtin_amdgcn_exp2f(-1.4426950408889634f * x);
    return __builtin_amdgcn_rcpf(1.0f + e);
}

__device__ __forceinline__ float tanh_f(float x) {
    float e = __builtin_amdgcn_exp2f(-2.8853900817779268f * x);
    return fmaf(2.0f, __builtin_amdgcn_rcpf(1.0f + e), -1.0f);
}

__global__ __launch_bounds__(256, 4)
void lstm_net_kernel(
    const float* __restrict__ x,      // [B, 1, T]
    const float* __restrict__ W_ih,   // [256, 1]
    const float* __restrict__ W_hh,   // [256, 64]
    const float* __restrict__ b_ih,   // [256]
    const float* __restrict__ b_hh,   // [256]
    const float* __restrict__ fc1_w,  // [64, 64]
    const float* __restrict__ fc1_b,  // [64]
    const float* __restrict__ fc2_w,  // [10, 64]
    const float* __restrict__ fc2_b,  // [10]
    float* __restrict__ out)          // [B, 10]
{
    const int lane = threadIdx.x & 63;
    const int wv   = threadIdx.x >> 6;   // gate index (i,f,g,o)
    const int b    = blockIdx.x;
    const int uw   = blockIdx.x & 3;     // update-wave id: rotates across SIMDs

    __shared__ __align__(16) float hbuf[HID];
    __shared__ float gbuf[4][HID];

    // This wave's gate row for lane k: W_hh[wv*64+lane][0:64] -> 32 v2f in VGPRs.
    const int row = wv * HID + lane;
    v2f wreg[HID / 2];
    {
        const float4* wrow = reinterpret_cast<const float4*>(W_hh + (size_t)row * HID);
        #pragma unroll
        for (int jj = 0; jj < HID / 4; ++jj) {
            float4 v = wrow[jj];
            wreg[2 * jj + 0] = (v2f){v.x, v.y};
            wreg[2 * jj + 1] = (v2f){v.z, v.w};
        }
    }
    #pragma unroll
    for (int p = 0; p < HID / 2; ++p) {
        asm volatile("" : "+v"(wreg[p]));  // defeat remat (cheap insurance, ~100 VGPR total)
    }

    const float wih  = W_ih[row];
    const float bsum = b_ih[row] + b_hh[row];

    const float* xrow = x + (size_t)b * T_STEPS;
    const float4* hb4 = reinterpret_cast<const float4*>(&hbuf[0]);

    // init h0 = 0
    if (threadIdx.x < HID) hbuf[threadIdx.x] = 0.0f;
    __syncthreads();

    float c = 0.0f;               // live only in the update wave
    float xt = xrow[0];           // wave-uniform

    #pragma unroll 1
    for (int t = 0; t < T_STEPS; ++t) {
        float xn = xrow[(t + 1 < T_STEPS) ? (t + 1) : t];

        // --- gate phase: a = bias + x*wih + dot(wreg, h) ---
        v2f acc0 = (v2f){fmaf(xt, wih, bsum), 0.0f};
        v2f acc1 = (v2f){0.0f, 0.0f};
        v2f acc2 = (v2f){0.0f, 0.0f};
        v2f acc3 = (v2f){0.0f, 0.0f};

        #pragma unroll
        for (int jj = 0; jj < HID / 4; ++jj) {
            float4 hv = hb4[jj];  // wave-uniform address -> LDS broadcast
            v2f h01 = (v2f){hv.x, hv.y};
            v2f h23 = (v2f){hv.z, hv.w};
            if (jj & 1) {
                acc2 = __builtin_elementwise_fma(wreg[2 * jj + 0], h01, acc2);
                acc3 = __builtin_elementwise_fma(wreg[2 * jj + 1], h23, acc3);
            } else {
                acc0 = __builtin_elementwise_fma(wreg[2 * jj + 0], h01, acc0);
                acc1 = __builtin_elementwise_fma(wreg[2 * jj + 1], h23, acc1);
            }
        }
        v2f s = (acc0 + acc1) + (acc2 + acc3);
        gbuf[wv][lane] = s.x + s.y;

        __syncthreads();  // gates visible

        if (wv == uw) {
            float a0 = gbuf[0][lane];
            float a1 = gbuf[1][lane];
            float a2 = gbuf[2][lane];
            float a3 = gbuf[3][lane];
            float ig = sigm(a0);
            float fg = sigm(a1);
            float gg = tanh_f(a2);
            float og = sigm(a3);
            c = fmaf(fg, c, ig * gg);
            hbuf[lane] = og * tanh_f(c);
        }

        __syncthreads();  // new h visible
        xt = xn;
    }

    // --- epilogue on the update wave: fc1 (relu) + fc2 ---
    if (wv == uw) {
        float acc = fc1_b[lane];
        const float4* w1 = reinterpret_cast<const float4*>(fc1_w + lane * HID);
        #pragma unroll
        for (int kk = 0; kk < HID / 4; ++kk) {
            float4 wvv = w1[kk];
            float4 hv  = hb4[kk];
            acc = fmaf(hv.x, wvv.x, acc);
            acc = fmaf(hv.y, wvv.y, acc);
            acc = fmaf(hv.z, wvv.z, acc);
            acc = fmaf(hv.w, wvv.w, acc);
        }
        gbuf[0][lane] = fmaxf(acc, 0.0f);  // intra-wave reuse; lockstep

        if (lane < NCLS) {
            float a = fc2_b[lane];
            const float* w2 = fc2_w + lane * HID;
            #pragma unroll
            for (int j = 0; j < HID; ++j) {
                a = fmaf(gbuf[0][j], w2[j], a);
            }
            out[(size_t)b * NCLS + lane] = a;
        }
    }
}

extern "C" void kernel_launch(void* const* d_in, const int* in_sizes, int n_in,
                              void* d_out, int out_size, void* d_ws, size_t ws_size,
                              hipStream_t stream) {
    const float* x     = (const float*)d_in[0];
    const float* W_ih  = (const float*)d_in[1];
    const float* W_hh  = (const float*)d_in[2];
    const float* b_ih  = (const float*)d_in[3];
    const float* b_hh  = (const float*)d_in[4];
    const float* fc1_w = (const float*)d_in[5];
    const float* fc1_b = (const float*)d_in[6];
    const float* fc2_w = (const float*)d_in[7];
    const float* fc2_b = (const float*)d_in[8];
    float* out = (float*)d_out;

    dim3 grid(1024);  // 1 block = 1 batch row
    dim3 block(256);  // 4 waves = 4 gates
    lstm_net_kernel<<<grid, block, 0, stream>>>(x, W_ih, W_hh, b_ih, b_hh,
                                                fc1_w, fc1_b, fc2_w, fc2_b, out);
}